// Round 1
// baseline (9320.423 us; speedup 1.0000x reference)
//
#include <hip/hip_runtime.h>
#include <hip/hip_bf16.h>

// ---------------------------------------------------------------------------
// Model: conv1d embed (+pos-embed) -> LSTM encoder (512 steps, B=64, H=512)
//        -> attention decoder (48 steps) -> linear proj.
// Strategy: big GEMMs (x@Wih.T, enc_part, xg) via bf16 MFMA NT-GEMM;
// recurrent parts via persistent kernels with device-scope spin barriers.
// ---------------------------------------------------------------------------

typedef short bf16x8 __attribute__((ext_vector_type(8)));
typedef float f32x4 __attribute__((ext_vector_type(4)));

__device__ __forceinline__ float bf2f(unsigned short u){
  return __uint_as_float(((unsigned)u) << 16);
}
__device__ __forceinline__ unsigned short f2bf(float f){
  unsigned x = __float_as_uint(f);
  unsigned r = (x + 0x7fffu + ((x >> 16) & 1u)) >> 16;   // RNE
  return (unsigned short)r;
}
__device__ __forceinline__ float sigm(float x){ return 1.f/(1.f + __expf(-x)); }
__device__ __forceinline__ float tanhfast(float x){
  float e = __expf(2.f*x);
  return 1.f - 2.f/(e + 1.f);
}

// Device-scope grid barrier: monotonic counter, zeroed by host memset.
__device__ __forceinline__ void grid_barrier(unsigned* bar, unsigned target){
  __syncthreads();
  if (threadIdx.x == 0){
    __hip_atomic_fetch_add(bar, 1u, __ATOMIC_RELEASE, __HIP_MEMORY_SCOPE_AGENT);
    while (__hip_atomic_load(bar, __ATOMIC_RELAXED, __HIP_MEMORY_SCOPE_AGENT) < target){
      __builtin_amdgcn_s_sleep(1);
    }
    (void)__hip_atomic_load(bar, __ATOMIC_ACQUIRE, __HIP_MEMORY_SCOPE_AGENT);
  }
  __syncthreads();
}

// ----------------------------- small utility kernels -----------------------

__global__ void cast_k(const float* __restrict__ src, unsigned short* __restrict__ dst, int n){
  int i = blockIdx.x*256 + threadIdx.x;
  if (i < n) dst[i] = f2bf(src[i]);
}

// attn_W (512 x 1024) -> Wh = attn_W[:, :512], We = attn_W[:, 512:]  (both bf16, K-contig)
__global__ void split_attn_k(const float* __restrict__ aw,
                             unsigned short* __restrict__ wh, unsigned short* __restrict__ we){
  int i = blockIdx.x*256 + threadIdx.x;      // 0 .. 512*512-1
  int nrow = i >> 9, k = i & 511;
  wh[i] = f2bf(aw[(size_t)nrow*1024 + k]);
  we[i] = f2bf(aw[(size_t)nrow*1024 + 512 + k]);
}

// conv1d (kernel 3, circular pad) + positional embedding; writes bf16.
// mode 0: out[(l*B + b)*512 + o]   (t-major, encoder)
// mode 1: out[((b*lcount + (l-l0))*512 + o]  (b-major slice, decoder)
__global__ __launch_bounds__(512) void embed_k(const float* __restrict__ x,
    const float* __restrict__ wconv, unsigned short* __restrict__ out,
    int Bsz, int Lx, int l0, int lcount, int mode){
  __shared__ float wl[512*21];
  __shared__ float xl[66*7];
  int nch = (lcount + 63) / 64;
  int b = blockIdx.x / nch, ci = blockIdx.x % nch;
  int tid = threadIdx.x;
  for (int i = tid; i < 512*21; i += 512) wl[i] = wconv[i];
  int lstart = l0 + ci*64;
  int cnt = l0 + lcount - lstart; if (cnt > 64) cnt = 64;
  int nwin = (cnt + 2) * 7;
  for (int i = tid; i < nwin; i += 512){
    int wr = i / 7, c = i % 7;
    int gl = lstart - 1 + wr;
    gl = (gl + Lx) % Lx;
    xl[i] = x[((size_t)b*Lx + gl)*7 + c];
  }
  __syncthreads();
  int o = tid;
  float fe = (float)(o & ~1);
  float div = __expf(fe * -0.0179889461f);   // -ln(10000)/512
  const float* wrow = &wl[o*21];
  for (int li = 0; li < cnt; ++li){
    int l = lstart + li;
    float acc = 0.f;
    #pragma unroll
    for (int c = 0; c < 7; ++c){
      #pragma unroll
      for (int kk = 0; kk < 3; ++kk)
        acc += xl[(li + kk)*7 + c] * wrow[c*3 + kk];
    }
    float arg = (float)l * div;
    acc += (o & 1) ? cosf(arg) : sinf(arg);
    size_t oi = mode ? (((size_t)b*lcount + (l - l0))*512 + o)
                     : (((size_t)l*Bsz + b)*512 + o);
    out[oi] = f2bf(acc);
  }
}

// ----------------------------- bf16 NT GEMM --------------------------------
// C[m][n] = sum_k A[m][k]*Bw[n][k] + bias[n], all row-major, K-contiguous.
// 128x128 tile, BK=32, 4 waves (2x2), mfma_f32_16x16x32_bf16. C stored bf16.
__global__ __launch_bounds__(256) void gemm_nt(const unsigned short* __restrict__ A,
    const unsigned short* __restrict__ Bw, const float* __restrict__ bias,
    unsigned short* __restrict__ C, int M, int N, int K){
  __shared__ __align__(16) unsigned short Asm[128*40];
  __shared__ __align__(16) unsigned short Bsm[128*40];
  const int tid = threadIdx.x;
  const int m0 = blockIdx.y * 128, n0 = blockIdx.x * 128;
  const int lane = tid & 63;
  const int wid = tid >> 6;
  const int wm = (wid >> 1) * 64, wn = (wid & 1) * 64;
  const int fr = lane & 15, q = lane >> 4;
  f32x4 acc[4][4];
  #pragma unroll
  for (int i=0;i<4;i++)
    #pragma unroll
    for(int j=0;j<4;j++) acc[i][j] = (f32x4){0.f,0.f,0.f,0.f};
  for (int k0 = 0; k0 < K; k0 += 32){
    #pragma unroll
    for (int c = 0; c < 2; ++c){
      int ch = tid + c*256;
      int r = ch >> 2, s = (ch & 3) * 8;
      *(uint4*)&Asm[r*40 + s] = *(const uint4*)&A[(size_t)(m0 + r)*K + k0 + s];
      *(uint4*)&Bsm[r*40 + s] = *(const uint4*)&Bw[(size_t)(n0 + r)*K + k0 + s];
    }
    __syncthreads();
    bf16x8 af[4], bfv[4];
    #pragma unroll
    for (int i=0;i<4;i++){
      af[i]  = *(const bf16x8*)&Asm[(wm + i*16 + fr)*40 + q*8];
      bfv[i] = *(const bf16x8*)&Bsm[(wn + i*16 + fr)*40 + q*8];
    }
    #pragma unroll
    for (int i=0;i<4;i++)
      #pragma unroll
      for (int j=0;j<4;j++)
        acc[i][j] = __builtin_amdgcn_mfma_f32_16x16x32_bf16(af[i], bfv[j], acc[i][j], 0,0,0);
    __syncthreads();
  }
  #pragma unroll
  for (int i=0;i<4;i++){
    #pragma unroll
    for (int j=0;j<4;j++){
      int n = n0 + wn + j*16 + fr;
      float bv = bias ? bias[n] : 0.f;
      #pragma unroll
      for (int r=0;r<4;r++){
        int m = m0 + wm + i*16 + q*4 + r;
        C[(size_t)m*N + n] = f2bf(acc[i][j][r] + bv);
      }
    }
  }
}

// ----------------------------- encoder LSTM --------------------------------
// 64 blocks x 256 thr. Block blk owns hidden units [8blk, 8blk+8) (x4 gates =
// 32 weight rows resident in LDS). One grid barrier per step.
__global__ __launch_bounds__(256) void lstm_enc(
    const unsigned short* __restrict__ xw,    // [nsteps][64][2048] bf16 (bias folded)
    const unsigned short* __restrict__ whh,   // [2048][512] bf16
    float* __restrict__ cbuf,                 // [64][512]
    unsigned short* __restrict__ hbuf,        // [2][64][512] bf16
    unsigned short* __restrict__ encout,      // [64][512][512] bf16
    int t0, int nsteps, unsigned* __restrict__ bar){
  __shared__ __align__(16) unsigned short wlds[32*520];
  __shared__ float gbuf[64*33];
  const int tid = threadIdx.x;
  const int blk = blockIdx.x;
  const int u0 = blk * 8;
  {
    int n = tid >> 3, seg = (tid & 7) * 64;
    int R = (n >> 3) * 512 + u0 + (n & 7);    // [i(8), f(8), g(8), o(8)]
    #pragma unroll
    for (int e = 0; e < 64; e += 8)
      *(uint4*)&wlds[n*520 + seg + e] = *(const uint4*)&whh[(size_t)R*512 + seg + e];
  }
  const int m0p = tid >> 3, j0 = tid & 7;
  const int m1p = (tid + 256) >> 3, j1 = tid & 7;
  __syncthreads();
  float c0 = cbuf[m0p*512 + u0 + j0];
  float c1 = cbuf[m1p*512 + u0 + j1];
  const int lane = tid & 63, wv = tid >> 6, fr = lane & 15, q = lane >> 4;
  for (int s = 0; s < nsteps; ++s){
    const int t = t0 + s;
    const int rp = t & 1, wp = rp ^ 1;
    f32x4 a0 = {0.f,0.f,0.f,0.f}, a1 = {0.f,0.f,0.f,0.f};
    const unsigned short* hb = hbuf + (size_t)rp * (64*512);
    #pragma unroll 4
    for (int k0 = 0; k0 < 512; k0 += 32){
      bf16x8 av = *(const bf16x8*)&hb[(size_t)(wv*16 + fr)*512 + k0 + q*8];
      bf16x8 b0 = *(const bf16x8*)&wlds[fr*520 + k0 + q*8];
      bf16x8 b1 = *(const bf16x8*)&wlds[(16 + fr)*520 + k0 + q*8];
      a0 = __builtin_amdgcn_mfma_f32_16x16x32_bf16(av, b0, a0, 0,0,0);
      a1 = __builtin_amdgcn_mfma_f32_16x16x32_bf16(av, b1, a1, 0,0,0);
    }
    #pragma unroll
    for (int r = 0; r < 4; ++r){
      gbuf[(wv*16 + q*4 + r)*33 + fr]      = a0[r];
      gbuf[(wv*16 + q*4 + r)*33 + 16 + fr] = a1[r];
    }
    __syncthreads();
    {
      const float* gb = &gbuf[m0p*33];
      size_t xi = ((size_t)s*64 + m0p)*2048 + u0 + j0;
      float gi = gb[j0]      + bf2f(xw[xi]);
      float gf = gb[8 + j0]  + bf2f(xw[xi + 512]);
      float gg = gb[16 + j0] + bf2f(xw[xi + 1024]);
      float go = gb[24 + j0] + bf2f(xw[xi + 1536]);
      float cc = sigm(gf)*c0 + sigm(gi)*tanhfast(gg);
      float hh = sigm(go)*tanhfast(cc);
      c0 = cc;
      unsigned short hv = f2bf(hh);
      hbuf[(size_t)wp*(64*512) + m0p*512 + u0 + j0] = hv;
      encout[((size_t)m0p*512 + t)*512 + u0 + j0] = hv;
    }
    {
      const float* gb = &gbuf[m1p*33];
      size_t xi = ((size_t)s*64 + m1p)*2048 + u0 + j1;
      float gi = gb[j1]      + bf2f(xw[xi]);
      float gf = gb[8 + j1]  + bf2f(xw[xi + 512]);
      float gg = gb[16 + j1] + bf2f(xw[xi + 1024]);
      float go = gb[24 + j1] + bf2f(xw[xi + 1536]);
      float cc = sigm(gf)*c1 + sigm(gi)*tanhfast(gg);
      float hh = sigm(go)*tanhfast(cc);
      c1 = cc;
      unsigned short hv = f2bf(hh);
      hbuf[(size_t)wp*(64*512) + m1p*512 + u0 + j1] = hv;
      encout[((size_t)m1p*512 + t)*512 + u0 + j1] = hv;
    }
    if (s == nsteps - 1){
      cbuf[m0p*512 + u0 + j0] = c0;
      cbuf[m1p*512 + u0 + j1] = c1;
    }
    grid_barrier(bar, 64u * (unsigned)(s + 1));
  }
}

// ----------------------------- decoder -------------------------------------
// 256 blocks x 256 thr, 48 steps, 4 grid barriers/step.
//   blocks 0-127 : gates + (h,c) update       (phase a)
//   blocks 128-159: hWh = h @ Wh.T            (phase b)
//   all blocks   : scores (tanh attention)    (phase c)
//   all blocks   : softmax + ctx partials     (phase d)
//   blocks 192-255: fc out (overlaps next a)  (phase f)
__global__ __launch_bounds__(256) void lstm_dec(
    const unsigned short* __restrict__ xg,      // [64][48][2048] bf16 (bias folded)
    const unsigned short* __restrict__ whh,     // dec_Whh bf16 [2048][512]
    const unsigned short* __restrict__ whq,     // Wh bf16 [512][512]
    const unsigned short* __restrict__ fcw,     // fc_W bf16 [512][1024]
    const float* __restrict__ fcb, const float* __restrict__ vvec,
    const unsigned short* __restrict__ encpart, // [64*512][512] bf16
    const unsigned short* __restrict__ encout,  // [64*512][512] bf16
    unsigned short* __restrict__ hbuf, float* __restrict__ cbuf,
    float* __restrict__ hwh, float* __restrict__ scores, float* __restrict__ ctxp,
    unsigned short* __restrict__ outs, unsigned* __restrict__ bar){
  __shared__ __align__(16) unsigned short wlds[16*520];
  __shared__ __align__(16) unsigned short fcwlds[8*1032];
  __shared__ float gbuf[64*17];
  __shared__ float hwhlds[512];
  __shared__ float vlds[512];
  __shared__ float sclds[512];
  __shared__ float awlds[128];
  __shared__ float red[8];
  const int tid = threadIdx.x, blk = blockIdx.x;
  const int lane = tid & 63, wv = tid >> 6, fr = lane & 15, q = lane >> 4;
  if (blk < 128){
    int n = tid >> 4, seg = (tid & 15) * 32;
    int R = (n >> 2) * 512 + blk * 4 + (n & 3);   // [i(4), f(4), g(4), o(4)]
    #pragma unroll
    for (int e = 0; e < 32; e += 8)
      *(uint4*)&wlds[n*520 + seg + e] = *(const uint4*)&whh[(size_t)R*512 + seg + e];
  } else if (blk < 160){
    int n = tid >> 4, seg = (tid & 15) * 32;
    int R = (blk - 128) * 16 + n;
    #pragma unroll
    for (int e = 0; e < 32; e += 8)
      *(uint4*)&wlds[n*520 + seg + e] = *(const uint4*)&whq[(size_t)R*512 + seg + e];
  } else if (blk >= 192){
    int n = tid >> 5, seg = (tid & 31) * 32;
    int R = (blk - 192) * 8 + n;
    #pragma unroll
    for (int e = 0; e < 32; e += 8)
      *(uint4*)&fcwlds[n*1032 + seg + e] = *(const uint4*)&fcw[(size_t)R*1024 + seg + e];
  }
  vlds[tid] = vvec[tid]; vlds[tid+256] = vvec[tid+256];
  const int um = tid >> 2, uj = tid & 3;
  const int u0 = blk * 4;
  float cst = 0.f;
  if (blk < 128) cst = cbuf[um*512 + u0 + uj];
  const int ab = blk >> 2, lc = blk & 3;
  __syncthreads();
  unsigned bbase = 0;
  for (int t = 0; t < 48; ++t){
    const int rp = t & 1, wp = rp ^ 1;
    // ---- phase a: gates + h,c update (blocks 0-127)
    if (blk < 128){
      f32x4 a0 = {0.f,0.f,0.f,0.f};
      const unsigned short* hb = hbuf + (size_t)rp*(64*512);
      #pragma unroll 4
      for (int k0 = 0; k0 < 512; k0 += 32){
        bf16x8 av = *(const bf16x8*)&hb[(size_t)(wv*16 + fr)*512 + k0 + q*8];
        bf16x8 bv = *(const bf16x8*)&wlds[fr*520 + k0 + q*8];
        a0 = __builtin_amdgcn_mfma_f32_16x16x32_bf16(av, bv, a0, 0,0,0);
      }
      #pragma unroll
      for (int r = 0; r < 4; ++r) gbuf[(wv*16 + q*4 + r)*17 + fr] = a0[r];
      __syncthreads();
      {
        const float* gb = &gbuf[um*17];
        size_t xi = ((size_t)um*48 + t)*2048 + u0 + uj;
        float gi = gb[uj]      + bf2f(xg[xi]);
        float gf = gb[4 + uj]  + bf2f(xg[xi + 512]);
        float gg = gb[8 + uj]  + bf2f(xg[xi + 1024]);
        float go = gb[12 + uj] + bf2f(xg[xi + 1536]);
        float cc = sigm(gf)*cst + sigm(gi)*tanhfast(gg);
        float hh = sigm(go)*tanhfast(cc);
        cst = cc;
        hbuf[(size_t)wp*(64*512) + um*512 + u0 + uj] = f2bf(hh);
      }
    }
    grid_barrier(bar, 256u*(bbase + 1));
    // ---- phase b: hWh (blocks 128-159)
    if (blk >= 128 && blk < 160){
      f32x4 a0 = {0.f,0.f,0.f,0.f};
      const unsigned short* hb = hbuf + (size_t)wp*(64*512);
      #pragma unroll 4
      for (int k0 = 0; k0 < 512; k0 += 32){
        bf16x8 av = *(const bf16x8*)&hb[(size_t)(wv*16 + fr)*512 + k0 + q*8];
        bf16x8 bv = *(const bf16x8*)&wlds[fr*520 + k0 + q*8];
        a0 = __builtin_amdgcn_mfma_f32_16x16x32_bf16(av, bv, a0, 0,0,0);
      }
      int r0 = (blk - 128) * 16;
      #pragma unroll
      for (int r = 0; r < 4; ++r)
        hwh[(size_t)(wv*16 + q*4 + r)*512 + r0 + fr] = a0[r];
    }
    grid_barrier(bar, 256u*(bbase + 2));
    // ---- phase c: scores (all blocks; block = (batch ab, l-chunk lc))
    {
      hwhlds[tid]     = hwh[ab*512 + tid];
      hwhlds[tid+256] = hwh[ab*512 + tid + 256];
      __syncthreads();
      int l = lc*128 + (tid >> 1);
      int half = tid & 1, k0 = half * 256;
      const unsigned short* ep = encpart + ((size_t)ab*512 + l)*512 + k0;
      float sacc = 0.f;
      for (int kk = 0; kk < 256; kk += 8){
        bf16x8 e8 = *(const bf16x8*)&ep[kk];
        #pragma unroll
        for (int e = 0; e < 8; ++e){
          float xv = bf2f(((unsigned short*)&e8)[e]) + hwhlds[k0+kk+e];
          sacc += vlds[k0+kk+e] * tanhfast(xv);
        }
      }
      sacc += __shfl_xor(sacc, 1);
      if (!half) scores[ab*512 + l] = sacc;
    }
    grid_barrier(bar, 256u*(bbase + 3));
    // ---- phase d: softmax + ctx partial
    {
      float v0 = scores[ab*512 + tid], v1 = scores[ab*512 + tid + 256];
      sclds[tid] = v0; sclds[tid+256] = v1;
      float mx = fmaxf(v0, v1);
      #pragma unroll
      for (int off=32; off; off>>=1) mx = fmaxf(mx, __shfl_xor(mx, off));
      if (lane == 0) red[wv] = mx;
      __syncthreads();
      mx = fmaxf(fmaxf(red[0],red[1]), fmaxf(red[2],red[3]));
      __syncthreads();
      float ps = __expf(v0 - mx) + __expf(v1 - mx);
      #pragma unroll
      for (int off=32; off; off>>=1) ps += __shfl_xor(ps, off);
      if (lane == 0) red[wv] = ps;
      __syncthreads();
      float inv = 1.f / (red[0]+red[1]+red[2]+red[3]);
      if (tid < 128) awlds[tid] = __expf(sclds[lc*128 + tid] - mx) * inv;
      __syncthreads();
      float ax = 0.f, ay = 0.f;
      const unsigned short* eo = encout + ((size_t)ab*512 + lc*128)*512 + 2*tid;
      for (int il = 0; il < 128; ++il){
        float aww = awlds[il];
        unsigned ee = *(const unsigned*)(eo + (size_t)il*512);
        ax += aww * __uint_as_float((ee & 0xffffu) << 16);
        ay += aww * __uint_as_float(ee & 0xffff0000u);
      }
      ctxp[(size_t)blk*512 + 2*tid]     = ax;
      ctxp[(size_t)blk*512 + 2*tid + 1] = ay;
    }
    grid_barrier(bar, 256u*(bbase + 4));
    // ---- phase f: fc output (blocks 192-255); overlaps next step's phase a
    if (blk >= 192){
      int r0 = (blk - 192) * 8;
      int m = tid >> 2, qq = tid & 3;
      float s8[8];
      #pragma unroll
      for (int r=0;r<8;r++) s8[r] = 0.f;
      const unsigned short* hb = hbuf + (size_t)wp*(64*512) + m*512;
      for (int c = 0; c < 16; ++c){
        int kk = (c*4 + qq) * 8;
        bf16x8 h8 = *(const bf16x8*)&hb[kk];
        float hf[8];
        #pragma unroll
        for (int e=0;e<8;e++) hf[e] = bf2f(((unsigned short*)&h8)[e]);
        #pragma unroll
        for (int r=0;r<8;r++){
          bf16x8 w8 = *(const bf16x8*)&fcwlds[r*1032 + kk];
          #pragma unroll
          for (int e=0;e<8;e++) s8[r] += hf[e]*bf2f(((unsigned short*)&w8)[e]);
        }
      }
      for (int c = 0; c < 16; ++c){
        int kk = (c*4 + qq) * 8;
        float cf[8];
        #pragma unroll
        for (int e=0;e<8;e++) cf[e] = 0.f;
        #pragma unroll
        for (int lcc = 0; lcc < 4; ++lcc){
          const float* cp = &ctxp[(size_t)(m*4 + lcc)*512 + kk];
          #pragma unroll
          for (int e=0;e<8;e++) cf[e] += cp[e];
        }
        #pragma unroll
        for (int r=0;r<8;r++){
          bf16x8 w8 = *(const bf16x8*)&fcwlds[r*1032 + 512 + kk];
          #pragma unroll
          for (int e=0;e<8;e++) s8[r] += cf[e]*bf2f(((unsigned short*)&w8)[e]);
        }
      }
      #pragma unroll
      for (int r=0;r<8;r++){
        s8[r] += __shfl_xor(s8[r], 1);
        s8[r] += __shfl_xor(s8[r], 2);
      }
      if (qq == 0){
        #pragma unroll
        for (int r=0;r<8;r++)
          outs[((size_t)m*48 + t)*512 + r0 + r] = f2bf(s8[r] + fcb[r0 + r]);
      }
    }
    bbase += 4;
  }
}

// ----------------------------- projection ----------------------------------
__global__ void proj_k(const unsigned short* __restrict__ outs,
                       const float* __restrict__ pw, const float* __restrict__ pb,
                       float* __restrict__ out){
  int gid = blockIdx.x*256 + threadIdx.x;
  if (gid >= 64*48*7) return;
  int row = gid / 7, oc = gid % 7;
  const unsigned short* orow = outs + (size_t)row*512;
  const float* wrow = pw + oc*512;
  float s = pb[oc];
  for (int k = 0; k < 512; k += 8){
    bf16x8 o8 = *(const bf16x8*)&orow[k];
    #pragma unroll
    for (int e=0;e<8;e++) s += bf2f(((unsigned short*)&o8)[e]) * wrow[k+e];
  }
  out[gid] = s;
}

// ----------------------------- launch --------------------------------------
extern "C" void kernel_launch(void* const* d_in, const int* in_sizes, int n_in,
                              void* d_out, int out_size, void* d_ws, size_t ws_size,
                              hipStream_t stream){
  (void)in_sizes; (void)n_in; (void)out_size; (void)ws_size;
  const float* x_enc   = (const float*)d_in[0];
  const float* x_dec   = (const float*)d_in[1];
  const float* w_emb_e = (const float*)d_in[2];
  const float* w_emb_d = (const float*)d_in[3];
  const float* enc_Wih = (const float*)d_in[4];
  const float* enc_Whh = (const float*)d_in[5];
  const float* enc_b   = (const float*)d_in[6];
  const float* dec_Wih = (const float*)d_in[7];
  const float* dec_Whh = (const float*)d_in[8];
  const float* dec_b   = (const float*)d_in[9];
  const float* attn_W  = (const float*)d_in[10];
  const float* attn_b  = (const float*)d_in[11];
  const float* vvec    = (const float*)d_in[12];
  const float* fc_W    = (const float*)d_in[13];
  const float* fc_b    = (const float*)d_in[14];
  const float* proj_W  = (const float*)d_in[15];
  const float* proj_b  = (const float*)d_in[16];
  float* out = (float*)d_out;

  char* ws = (char*)d_ws;
  size_t off = 0;
  auto alloc = [&](size_t bytes)->char*{
    char* p = ws + off;
    off = (off + bytes + 255) & ~(size_t)255;
    return p;
  };
  unsigned short* encxw  = (unsigned short*)alloc(128ull*64*2048*2); // per-chunk x@Wih.T
  unsigned short* encin  = (unsigned short*)alloc(512ull*64*512*2);  // embed (t-major); reused as enc_part
  unsigned short* encout = (unsigned short*)alloc(64ull*512*512*2);
  unsigned short* xs     = (unsigned short*)alloc(64ull*48*512*2);
  unsigned short* xg     = (unsigned short*)alloc(64ull*48*2048*2);
  unsigned short* outsb  = (unsigned short*)alloc(64ull*48*512*2);
  unsigned short* wih_e  = (unsigned short*)alloc(2048ull*512*2);
  unsigned short* whh_e  = (unsigned short*)alloc(2048ull*512*2);
  unsigned short* wih_d  = (unsigned short*)alloc(2048ull*512*2);
  unsigned short* whh_d  = (unsigned short*)alloc(2048ull*512*2);
  unsigned short* whq    = (unsigned short*)alloc(512ull*512*2);
  unsigned short* weq    = (unsigned short*)alloc(512ull*512*2);
  unsigned short* fcw    = (unsigned short*)alloc(512ull*1024*2);
  unsigned short* hbuf   = (unsigned short*)alloc(2ull*64*512*2);
  float* cbuf   = (float*)alloc(64ull*512*4);
  float* hwh    = (float*)alloc(64ull*512*4);
  float* scores = (float*)alloc(64ull*512*4);
  float* ctxp   = (float*)alloc(256ull*512*4);
  unsigned* bar = (unsigned*)alloc(1024);

  hipMemsetAsync(bar, 0, 1024, stream);
  hipMemsetAsync(hbuf, 0, 2ull*64*512*2, stream);
  hipMemsetAsync(cbuf, 0, 64ull*512*4, stream);

  cast_k<<<4096, 256, 0, stream>>>(enc_Wih, wih_e, 2048*512);
  cast_k<<<4096, 256, 0, stream>>>(enc_Whh, whh_e, 2048*512);
  cast_k<<<4096, 256, 0, stream>>>(dec_Wih, wih_d, 2048*512);
  cast_k<<<4096, 256, 0, stream>>>(dec_Whh, whh_d, 2048*512);
  cast_k<<<2048, 256, 0, stream>>>(fc_W, fcw, 512*1024);
  split_attn_k<<<1024, 256, 0, stream>>>(attn_W, whq, weq);

  embed_k<<<512, 512, 0, stream>>>(x_enc, w_emb_e, encin, 64, 512, 0, 512, 0);
  embed_k<<<64, 512, 0, stream>>>(x_dec, w_emb_d, xs, 64, 144, 48, 48, 1);

  gemm_nt<<<dim3(16, 24), 256, 0, stream>>>(xs, wih_d, dec_b, xg, 3072, 2048, 512);

  for (int c = 0; c < 4; ++c){
    gemm_nt<<<dim3(16, 64), 256, 0, stream>>>(encin + (size_t)c*8192*512, wih_e, enc_b,
                                              encxw, 8192, 2048, 512);
    lstm_enc<<<64, 256, 0, stream>>>(encxw, whh_e, cbuf, hbuf, encout, c*128, 128, bar + c*16);
  }

  gemm_nt<<<dim3(4, 256), 256, 0, stream>>>(encout, weq, attn_b, encin /*enc_part*/, 32768, 512, 512);

  lstm_dec<<<256, 256, 0, stream>>>(xg, whh_d, whq, fcw, fc_b, vvec,
                                    encin /*enc_part*/, encout, hbuf, cbuf,
                                    hwh, scores, ctxp, outsb, bar + 64);

  proj_k<<<84, 256, 0, stream>>>(outsb, proj_W, proj_b, out);
}

// Round 2
// 6831.956 us; speedup vs baseline: 1.3642x; 1.3642x over previous
//
#include <hip/hip_runtime.h>
#include <hip/hip_bf16.h>

// ---------------------------------------------------------------------------
// conv1d embed -> LSTM encoder (512 steps, B=64, H=512) -> attention decoder
// (48 steps) -> projection.  GEMMs via bf16 MFMA; recurrences via persistent
// kernels with slot-based (store+poll, no RMW) grid barriers.
// Encoder: 4 independent batch-groups x 32 blocks (own barrier domain).
// Decoder: 3 barriers/step; hWh folded into score phase per k-slice.
// ---------------------------------------------------------------------------

typedef short bf16x8 __attribute__((ext_vector_type(8)));
typedef float f32x4 __attribute__((ext_vector_type(4)));

__device__ __forceinline__ float bf2f(unsigned short u){
  return __uint_as_float(((unsigned)u) << 16);
}
__device__ __forceinline__ unsigned short f2bf(float f){
  unsigned x = __float_as_uint(f);
  unsigned r = (x + 0x7fffu + ((x >> 16) & 1u)) >> 16;   // RNE
  return (unsigned short)r;
}
__device__ __forceinline__ float sigm(float x){
  return __builtin_amdgcn_rcpf(1.f + __builtin_amdgcn_exp2f(-1.44269504f*x));
}
__device__ __forceinline__ float tanh2(float x){
  return 1.f - 2.f*__builtin_amdgcn_rcpf(1.f + __builtin_amdgcn_exp2f(2.88539008f*x));
}

// Slot barrier: block stores monotonically-increasing target to its own slot
// (release); wave 0 polls all slots (relaxed) until min >= target, then one
// acquire load. No same-address RMW serialization.
__device__ __forceinline__ void slot_barrier(unsigned* myslot, const unsigned* slots,
                                             int nslots, unsigned target){
  __syncthreads();
  if (threadIdx.x == 0)
    __hip_atomic_store(myslot, target, __ATOMIC_RELEASE, __HIP_MEMORY_SCOPE_AGENT);
  if (threadIdx.x < 64){
    while (true){
      bool ok = true;
      for (int i = threadIdx.x; i < nslots; i += 64)
        ok &= (__hip_atomic_load(&slots[i], __ATOMIC_RELAXED, __HIP_MEMORY_SCOPE_AGENT) >= target);
      if (__all(ok)) break;
      __builtin_amdgcn_s_sleep(1);
    }
    if (threadIdx.x == 0)
      (void)__hip_atomic_load(&slots[0], __ATOMIC_ACQUIRE, __HIP_MEMORY_SCOPE_AGENT);
  }
  __syncthreads();
}

// ----------------------------- small utility kernels -----------------------

__global__ void cast_k(const float* __restrict__ src, unsigned short* __restrict__ dst, int n){
  int i = blockIdx.x*256 + threadIdx.x;
  if (i < n) dst[i] = f2bf(src[i]);
}

__global__ void split_attn_k(const float* __restrict__ aw,
                             unsigned short* __restrict__ wh, unsigned short* __restrict__ we){
  int i = blockIdx.x*256 + threadIdx.x;
  int nrow = i >> 9, k = i & 511;
  wh[i] = f2bf(aw[(size_t)nrow*1024 + k]);
  we[i] = f2bf(aw[(size_t)nrow*1024 + 512 + k]);
}

// conv1d (kernel 3, circular pad) + positional embedding; writes bf16.
__global__ __launch_bounds__(512) void embed_k(const float* __restrict__ x,
    const float* __restrict__ wconv, unsigned short* __restrict__ out,
    int Bsz, int Lx, int l0, int lcount, int mode){
  __shared__ float wl[512*21];
  __shared__ float xl[66*7];
  int nch = (lcount + 63) / 64;
  int b = blockIdx.x / nch, ci = blockIdx.x % nch;
  int tid = threadIdx.x;
  for (int i = tid; i < 512*21; i += 512) wl[i] = wconv[i];
  int lstart = l0 + ci*64;
  int cnt = l0 + lcount - lstart; if (cnt > 64) cnt = 64;
  int nwin = (cnt + 2) * 7;
  for (int i = tid; i < nwin; i += 512){
    int wr = i / 7, c = i % 7;
    int gl = lstart - 1 + wr;
    gl = (gl + Lx) % Lx;
    xl[i] = x[((size_t)b*Lx + gl)*7 + c];
  }
  __syncthreads();
  int o = tid;
  float fe = (float)(o & ~1);
  float div = __expf(fe * -0.0179889461f);
  const float* wrow = &wl[o*21];
  for (int li = 0; li < cnt; ++li){
    int l = lstart + li;
    float acc = 0.f;
    #pragma unroll
    for (int c = 0; c < 7; ++c)
      #pragma unroll
      for (int kk = 0; kk < 3; ++kk)
        acc += xl[(li + kk)*7 + c] * wrow[c*3 + kk];
    float arg = (float)l * div;
    acc += (o & 1) ? cosf(arg) : sinf(arg);
    size_t oi = mode ? (((size_t)b*lcount + (l - l0))*512 + o)
                     : (((size_t)l*Bsz + b)*512 + o);
    out[oi] = f2bf(acc);
  }
}

// ----------------------------- bf16 NT GEMM --------------------------------
__global__ __launch_bounds__(256) void gemm_nt(const unsigned short* __restrict__ A,
    const unsigned short* __restrict__ Bw, const float* __restrict__ bias,
    unsigned short* __restrict__ C, int M, int N, int K){
  __shared__ __align__(16) unsigned short Asm[128*40];
  __shared__ __align__(16) unsigned short Bsm[128*40];
  const int tid = threadIdx.x;
  const int m0 = blockIdx.y * 128, n0 = blockIdx.x * 128;
  const int lane = tid & 63;
  const int wid = tid >> 6;
  const int wm = (wid >> 1) * 64, wn = (wid & 1) * 64;
  const int fr = lane & 15, q = lane >> 4;
  f32x4 acc[4][4];
  #pragma unroll
  for (int i=0;i<4;i++)
    #pragma unroll
    for(int j=0;j<4;j++) acc[i][j] = (f32x4){0.f,0.f,0.f,0.f};
  for (int k0 = 0; k0 < K; k0 += 32){
    #pragma unroll
    for (int c = 0; c < 2; ++c){
      int ch = tid + c*256;
      int r = ch >> 2, s = (ch & 3) * 8;
      *(uint4*)&Asm[r*40 + s] = *(const uint4*)&A[(size_t)(m0 + r)*K + k0 + s];
      *(uint4*)&Bsm[r*40 + s] = *(const uint4*)&Bw[(size_t)(n0 + r)*K + k0 + s];
    }
    __syncthreads();
    bf16x8 af[4], bfv[4];
    #pragma unroll
    for (int i=0;i<4;i++){
      af[i]  = *(const bf16x8*)&Asm[(wm + i*16 + fr)*40 + q*8];
      bfv[i] = *(const bf16x8*)&Bsm[(wn + i*16 + fr)*40 + q*8];
    }
    #pragma unroll
    for (int i=0;i<4;i++)
      #pragma unroll
      for (int j=0;j<4;j++)
        acc[i][j] = __builtin_amdgcn_mfma_f32_16x16x32_bf16(af[i], bfv[j], acc[i][j], 0,0,0);
    __syncthreads();
  }
  #pragma unroll
  for (int i=0;i<4;i++){
    #pragma unroll
    for (int j=0;j<4;j++){
      int n = n0 + wn + j*16 + fr;
      float bv = bias ? bias[n] : 0.f;
      #pragma unroll
      for (int r=0;r<4;r++){
        int m = m0 + wm + i*16 + q*4 + r;
        C[(size_t)m*N + n] = f2bf(acc[i][j][r] + bv);
      }
    }
  }
}

// ----------------------------- encoder LSTM --------------------------------
// 128 blocks = 4 batch-groups (16 batches) x 32 unit-blocks (16 units each).
// Each group syncs only its own 32 blocks (32-slot barrier).
__global__ __launch_bounds__(256) void lstm_enc(
    const unsigned short* __restrict__ xw,    // [nsteps][64][2048] bf16 (bias folded)
    const unsigned short* __restrict__ whh,   // [2048][512] bf16
    float* __restrict__ cbuf,                 // [64][512]
    unsigned short* __restrict__ hbuf,        // [2][64][512] bf16
    unsigned short* __restrict__ encout,      // [64][512][512] bf16
    int t0, int nsteps, unsigned* __restrict__ slots){
  __shared__ __align__(16) unsigned short wlds[64*516];
  __shared__ float gbuf[16*68];
  const int tid = threadIdx.x;
  const int g = blockIdx.x >> 5;      // batch group 0..3
  const int j = blockIdx.x & 31;      // unit block 0..31
  const int b0 = g*16, u0 = j*16;
  // rows n: gate = n>>4, unit = u0 + (n&15)
  for (int idx = tid; idx < 64*64; idx += 256){
    int n = idx >> 6, ch = idx & 63;
    int R = (n >> 4)*512 + u0 + (n & 15);
    *(uint4*)&wlds[n*516 + ch*8] = *(const uint4*)&whh[(size_t)R*512 + ch*8];
  }
  __syncthreads();
  const int lane = tid & 63, wv = tid >> 6, fr = lane & 15, q = lane >> 4;
  const int m = tid >> 4, j2 = tid & 15;
  float cst = cbuf[(b0 + m)*512 + u0 + j2];
  unsigned* myslot = slots + g*64 + j;
  const unsigned* gslots = slots + g*64;
  for (int s = 0; s < nsteps; ++s){
    const int t = t0 + s;
    const int rp = t & 1, wp = rp ^ 1;
    const unsigned short* hb = hbuf + (size_t)rp*(64*512) + (size_t)b0*512;
    f32x4 acc = {0.f,0.f,0.f,0.f};
    #pragma unroll
    for (int k0 = 0; k0 < 512; k0 += 32){
      bf16x8 av = *(const bf16x8*)&hb[(size_t)fr*512 + k0 + q*8];
      bf16x8 bv = *(const bf16x8*)&wlds[(wv*16 + fr)*516 + k0 + q*8];
      acc = __builtin_amdgcn_mfma_f32_16x16x32_bf16(av, bv, acc, 0,0,0);
    }
    #pragma unroll
    for (int r = 0; r < 4; ++r)
      gbuf[(q*4 + r)*68 + wv*16 + fr] = acc[r];
    __syncthreads();
    {
      size_t xi = ((size_t)s*64 + b0 + m)*2048 + u0 + j2;
      float gi = gbuf[m*68 + j2]      + bf2f(xw[xi]);
      float gf = gbuf[m*68 + 16 + j2] + bf2f(xw[xi + 512]);
      float gg = gbuf[m*68 + 32 + j2] + bf2f(xw[xi + 1024]);
      float go = gbuf[m*68 + 48 + j2] + bf2f(xw[xi + 1536]);
      float cc = sigm(gf)*cst + sigm(gi)*tanh2(gg);
      float hh = sigm(go)*tanh2(cc);
      cst = cc;
      unsigned short hv = f2bf(hh);
      hbuf[(size_t)wp*(64*512) + (b0+m)*512 + u0 + j2] = hv;
      encout[((size_t)(b0+m)*512 + t)*512 + u0 + j2] = hv;
    }
    if (s == nsteps - 1) cbuf[(b0+m)*512 + u0 + j2] = cst;
    slot_barrier(myslot, gslots, 32, (unsigned)(t + 1));
  }
}

// ----------------------------- decoder -------------------------------------
// 256 blocks x 256 thr, 48 steps, 3 slot-barriers/step.
// Phase A: blocks 0-127 gates (4 units); blocks 128-255 fc of step t-1.
// Phase C: all blocks (ab=blk>>2, ks=blk&3): own hwh k-slice via MFMA
//          (Wh slice LDS-resident) + partial scores over all 512 l.
// Phase D: all blocks (ab, lc=ks): sum 4 score partials, softmax, ctx partial.
__global__ __launch_bounds__(256) void lstm_dec(
    const unsigned short* __restrict__ xg,      // [64][48][2048] bf16 (bias folded)
    const unsigned short* __restrict__ whh,     // dec_Whh bf16 [2048][512]
    const unsigned short* __restrict__ whq,     // Wh bf16 [512][512]
    const unsigned short* __restrict__ fcw,     // fc_W bf16 [512][1024]
    const float* __restrict__ fcb, const float* __restrict__ vvec,
    const unsigned short* __restrict__ encpart, // [64*512][512] bf16
    const unsigned short* __restrict__ encout,  // [64*512][512] bf16
    unsigned short* __restrict__ hbuf, float* __restrict__ cbuf,
    float* __restrict__ scp,                    // [64][4][512] score partials
    float* __restrict__ ctxp,                   // [256][512] ctx partials
    unsigned short* __restrict__ outs, unsigned* __restrict__ slots){
  __shared__ __align__(16) unsigned short Whsl[128*516];
  __shared__ __align__(16) unsigned short wshare[16*516];
  __shared__ __align__(16) unsigned short hlds[512];
  __shared__ __align__(16) float hwhlds[128];
  __shared__ float gbuf[64*17];
  __shared__ float sclds[512];
  __shared__ float awlds[128];
  __shared__ __align__(16) float vlds[512];
  __shared__ float red[8];
  const int tid = threadIdx.x, blk = blockIdx.x;
  const int lane = tid & 63, wv = tid >> 6, fr = lane & 15, q = lane >> 4;
  const int ab = blk >> 2, ks = blk & 3;
  // Wh slice rows [ks*128, ks*128+128)
  for (int idx = tid; idx < 128*64; idx += 256){
    int r = idx >> 6, ch = idx & 63;
    *(uint4*)&Whsl[r*516 + ch*8] = *(const uint4*)&whq[((size_t)(ks*128 + r))*512 + ch*8];
  }
  if (blk < 128){
    for (int idx = tid; idx < 16*64; idx += 256){
      int n = idx >> 6, ch = idx & 63;
      int R = (n >> 2)*512 + blk*4 + (n & 3);   // [i(4), f(4), g(4), o(4)]
      *(uint4*)&wshare[n*516 + ch*8] = *(const uint4*)&whh[(size_t)R*512 + ch*8];
    }
  } else {
    int fb = blk - 128;
    for (int idx = tid; idx < 4*128; idx += 256){
      int r = idx >> 7, ch = idx & 127;
      *(uint4*)&wshare[r*1032 + ch*8] = *(const uint4*)&fcw[((size_t)(fb*4 + r))*1024 + ch*8];
    }
  }
  vlds[tid] = vvec[tid]; vlds[tid+256] = vvec[tid+256];
  __syncthreads();
  // precompute: vsum over this block's k-slice; then vlds := -2*v
  float vsum = 0.f;
  for (int k = 0; k < 128; ++k) vsum += vlds[ks*128 + k];
  __syncthreads();
  vlds[tid] *= -2.f; vlds[tid+256] *= -2.f;
  const int um = tid >> 2, uj = tid & 3;
  float cst = (blk < 128) ? cbuf[um*512 + blk*4 + uj] : 0.f;
  unsigned* myslot = slots + blk;

  auto do_fc = [&](int tt){
    int fb = blk - 128, r0 = fb*4;
    int fm = tid >> 2, qq = tid & 3;
    int hp = (tt + 1) & 1;
    const unsigned short* hb = hbuf + (size_t)hp*(64*512) + (size_t)fm*512;
    float s4[4] = {0.f,0.f,0.f,0.f};
    for (int c = 0; c < 16; ++c){
      int kk = (c*4 + qq)*8;
      bf16x8 h8 = *(const bf16x8*)&hb[kk];
      float hf[8];
      #pragma unroll
      for (int e=0;e<8;e++) hf[e] = bf2f(((const unsigned short*)&h8)[e]);
      #pragma unroll
      for (int r = 0; r < 4; ++r){
        bf16x8 w8 = *(const bf16x8*)&wshare[r*1032 + kk];
        #pragma unroll
        for (int e = 0; e < 8; ++e)
          s4[r] += hf[e] * bf2f(((const unsigned short*)&w8)[e]);
      }
    }
    for (int c = 0; c < 16; ++c){
      int kk = (c*4 + qq)*8;
      float cf[8];
      #pragma unroll
      for (int e = 0; e < 8; ++e) cf[e] = 0.f;
      #pragma unroll
      for (int l = 0; l < 4; ++l){
        const float* cp = &ctxp[((size_t)(fm*4 + l))*512 + kk];
        #pragma unroll
        for (int e = 0; e < 8; ++e) cf[e] += cp[e];
      }
      #pragma unroll
      for (int r = 0; r < 4; ++r){
        bf16x8 w8 = *(const bf16x8*)&wshare[r*1032 + 512 + kk];
        #pragma unroll
        for (int e = 0; e < 8; ++e)
          s4[r] += cf[e] * bf2f(((const unsigned short*)&w8)[e]);
      }
    }
    #pragma unroll
    for (int r = 0; r < 4; ++r){
      s4[r] += __shfl_xor(s4[r], 1);
      s4[r] += __shfl_xor(s4[r], 2);
    }
    if (qq == 0){
      #pragma unroll
      for (int r = 0; r < 4; ++r)
        outs[((size_t)fm*48 + tt)*512 + r0 + r] = f2bf(s4[r] + fcb[r0 + r]);
    }
  };

  for (int t = 0; t < 48; ++t){
    const int rp = t & 1, wp = rp ^ 1;
    // ---- phase A: gates (0-127) | fc of t-1 (128-255)
    if (blk < 128){
      const unsigned short* hb = hbuf + (size_t)rp*(64*512);
      f32x4 a0 = {0.f,0.f,0.f,0.f};
      #pragma unroll
      for (int k0 = 0; k0 < 512; k0 += 32){
        bf16x8 av = *(const bf16x8*)&hb[(size_t)(wv*16 + fr)*512 + k0 + q*8];
        bf16x8 bv = *(const bf16x8*)&wshare[fr*516 + k0 + q*8];
        a0 = __builtin_amdgcn_mfma_f32_16x16x32_bf16(av, bv, a0, 0,0,0);
      }
      #pragma unroll
      for (int r = 0; r < 4; ++r) gbuf[(wv*16 + q*4 + r)*17 + fr] = a0[r];
      __syncthreads();
      {
        const float* gb = &gbuf[um*17];
        size_t xi = ((size_t)um*48 + t)*2048 + blk*4 + uj;
        float gi = gb[uj]      + bf2f(xg[xi]);
        float gf = gb[4 + uj]  + bf2f(xg[xi + 512]);
        float gg = gb[8 + uj]  + bf2f(xg[xi + 1024]);
        float go = gb[12 + uj] + bf2f(xg[xi + 1536]);
        float cc = sigm(gf)*cst + sigm(gi)*tanh2(gg);
        float hh = sigm(go)*tanh2(cc);
        cst = cc;
        hbuf[(size_t)wp*(64*512) + um*512 + blk*4 + uj] = f2bf(hh);
      }
    } else if (t > 0){
      do_fc(t - 1);
    }
    slot_barrier(myslot, slots, 256, 3u*t + 1);
    // ---- phase C: own hwh k-slice (MFMA) + partial scores
    {
      *(unsigned*)&hlds[tid*2] = *(const unsigned*)&hbuf[(size_t)wp*(64*512) + ab*512 + tid*2];
      __syncthreads();
      f32x4 h0 = {0.f,0.f,0.f,0.f}, h1 = {0.f,0.f,0.f,0.f};
      #pragma unroll
      for (int k0 = 0; k0 < 512; k0 += 32){
        bf16x8 av = *(const bf16x8*)&hlds[k0 + q*8];   // broadcast across A-rows
        bf16x8 b0 = *(const bf16x8*)&Whsl[(wv*32 + fr)*516 + k0 + q*8];
        bf16x8 b1 = *(const bf16x8*)&Whsl[(wv*32 + 16 + fr)*516 + k0 + q*8];
        h0 = __builtin_amdgcn_mfma_f32_16x16x32_bf16(av, b0, h0, 0,0,0);
        h1 = __builtin_amdgcn_mfma_f32_16x16x32_bf16(av, b1, h1, 0,0,0);
      }
      if (q == 0){
        hwhlds[wv*32 + fr]      = 2.88539008f * h0[0];   // pre-scaled for exp2
        hwhlds[wv*32 + 16 + fr] = 2.88539008f * h1[0];
      }
      __syncthreads();
      // partial scores: score_l(ks) = vsum + sum_k (-2 v_k) * rcp(1+exp2(2.885*(ep+hwh)))
      const unsigned short* ep0 = encpart + ((size_t)ab*512 + tid)*512 + ks*128;
      const unsigned short* ep1 = ep0 + (size_t)256*512;
      float sacc0 = vsum, sacc1 = vsum;
      for (int kk = 0; kk < 128; kk += 8){
        bf16x8 e0 = *(const bf16x8*)&ep0[kk];
        bf16x8 e1 = *(const bf16x8*)&ep1[kk];
        float4 hwa = *(const float4*)&hwhlds[kk];
        float4 hwb = *(const float4*)&hwhlds[kk+4];
        float4 va  = *(const float4*)&vlds[ks*128 + kk];
        float4 vb  = *(const float4*)&vlds[ks*128 + kk + 4];
        float hw[8] = {hwa.x,hwa.y,hwa.z,hwa.w,hwb.x,hwb.y,hwb.z,hwb.w};
        float vv[8] = {va.x,va.y,va.z,va.w,vb.x,vb.y,vb.z,vb.w};
        #pragma unroll
        for (int e = 0; e < 8; ++e){
          float a0 = fmaf(bf2f(((const unsigned short*)&e0)[e]), 2.88539008f, hw[e]);
          float a1 = fmaf(bf2f(((const unsigned short*)&e1)[e]), 2.88539008f, hw[e]);
          sacc0 += vv[e]*__builtin_amdgcn_rcpf(1.f + __builtin_amdgcn_exp2f(a0));
          sacc1 += vv[e]*__builtin_amdgcn_rcpf(1.f + __builtin_amdgcn_exp2f(a1));
        }
      }
      scp[((size_t)ab*4 + ks)*512 + tid]       = sacc0;
      scp[((size_t)ab*4 + ks)*512 + tid + 256] = sacc1;
    }
    slot_barrier(myslot, slots, 256, 3u*t + 2);
    // ---- phase D: sum partials, softmax, ctx partial (lc = ks)
    {
      const int lc = ks;
      float v0 = 0.f, v1 = 0.f;
      #pragma unroll
      for (int kk = 0; kk < 4; ++kk){
        v0 += scp[((size_t)ab*4 + kk)*512 + tid];
        v1 += scp[((size_t)ab*4 + kk)*512 + tid + 256];
      }
      sclds[tid] = v0; sclds[tid+256] = v1;
      float mx = fmaxf(v0, v1);
      #pragma unroll
      for (int off=32; off; off>>=1) mx = fmaxf(mx, __shfl_xor(mx, off));
      if (lane == 0) red[wv] = mx;
      __syncthreads();
      mx = fmaxf(fmaxf(red[0],red[1]), fmaxf(red[2],red[3]));
      __syncthreads();
      float ps = __expf(v0 - mx) + __expf(v1 - mx);
      #pragma unroll
      for (int off=32; off; off>>=1) ps += __shfl_xor(ps, off);
      if (lane == 0) red[wv] = ps;
      __syncthreads();
      float inv = 1.f / (red[0]+red[1]+red[2]+red[3]);
      if (tid < 128) awlds[tid] = __expf(sclds[lc*128 + tid] - mx) * inv;
      __syncthreads();
      float ax = 0.f, ay = 0.f;
      const unsigned short* eo = encout + ((size_t)ab*512 + lc*128)*512 + 2*tid;
      #pragma unroll 4
      for (int il = 0; il < 128; ++il){
        float aww = awlds[il];
        unsigned ee = *(const unsigned*)(eo + (size_t)il*512);
        ax += aww * __uint_as_float((ee & 0xffffu) << 16);
        ay += aww * __uint_as_float(ee & 0xffff0000u);
      }
      ctxp[(size_t)blk*512 + 2*tid]     = ax;
      ctxp[(size_t)blk*512 + 2*tid + 1] = ay;
    }
    slot_barrier(myslot, slots, 256, 3u*t + 3);
  }
  if (blk >= 128) do_fc(47);
}

// ----------------------------- projection ----------------------------------
__global__ void proj_k(const unsigned short* __restrict__ outs,
                       const float* __restrict__ pw, const float* __restrict__ pb,
                       float* __restrict__ out){
  int gid = blockIdx.x*256 + threadIdx.x;
  if (gid >= 64*48*7) return;
  int row = gid / 7, oc = gid % 7;
  const unsigned short* orow = outs + (size_t)row*512;
  const float* wrow = pw + oc*512;
  float s = pb[oc];
  for (int k = 0; k < 512; k += 8){
    bf16x8 o8 = *(const bf16x8*)&orow[k];
    #pragma unroll
    for (int e=0;e<8;e++) s += bf2f(((unsigned short*)&o8)[e]) * wrow[k+e];
  }
  out[gid] = s;
}

// ----------------------------- launch --------------------------------------
extern "C" void kernel_launch(void* const* d_in, const int* in_sizes, int n_in,
                              void* d_out, int out_size, void* d_ws, size_t ws_size,
                              hipStream_t stream){
  (void)in_sizes; (void)n_in; (void)out_size; (void)ws_size;
  const float* x_enc   = (const float*)d_in[0];
  const float* x_dec   = (const float*)d_in[1];
  const float* w_emb_e = (const float*)d_in[2];
  const float* w_emb_d = (const float*)d_in[3];
  const float* enc_Wih = (const float*)d_in[4];
  const float* enc_Whh = (const float*)d_in[5];
  const float* enc_b   = (const float*)d_in[6];
  const float* dec_Wih = (const float*)d_in[7];
  const float* dec_Whh = (const float*)d_in[8];
  const float* dec_b   = (const float*)d_in[9];
  const float* attn_W  = (const float*)d_in[10];
  const float* attn_b  = (const float*)d_in[11];
  const float* vvec    = (const float*)d_in[12];
  const float* fc_W    = (const float*)d_in[13];
  const float* fc_b    = (const float*)d_in[14];
  const float* proj_W  = (const float*)d_in[15];
  const float* proj_b  = (const float*)d_in[16];
  float* out = (float*)d_out;

  char* ws = (char*)d_ws;
  size_t off = 0;
  auto alloc = [&](size_t bytes)->char*{
    char* p = ws + off;
    off = (off + bytes + 255) & ~(size_t)255;
    return p;
  };
  unsigned short* encxw  = (unsigned short*)alloc(128ull*64*2048*2);
  unsigned short* encin  = (unsigned short*)alloc(512ull*64*512*2);  // embed; reused as enc_part
  unsigned short* encout = (unsigned short*)alloc(64ull*512*512*2);
  unsigned short* xs     = (unsigned short*)alloc(64ull*48*512*2);
  unsigned short* xg     = (unsigned short*)alloc(64ull*48*2048*2);
  unsigned short* outsb  = (unsigned short*)alloc(64ull*48*512*2);
  unsigned short* wih_e  = (unsigned short*)alloc(2048ull*512*2);
  unsigned short* whh_e  = (unsigned short*)alloc(2048ull*512*2);
  unsigned short* wih_d  = (unsigned short*)alloc(2048ull*512*2);
  unsigned short* whh_d  = (unsigned short*)alloc(2048ull*512*2);
  unsigned short* whq    = (unsigned short*)alloc(512ull*512*2);
  unsigned short* weq    = (unsigned short*)alloc(512ull*512*2);
  unsigned short* fcw    = (unsigned short*)alloc(512ull*1024*2);
  unsigned short* hbuf   = (unsigned short*)alloc(2ull*64*512*2);
  float* cbuf   = (float*)alloc(64ull*512*4);
  float* scp    = (float*)alloc(64ull*4*512*4);
  float* ctxp   = (float*)alloc(256ull*512*4);
  unsigned* eslots = (unsigned*)alloc(4*64*4);
  unsigned* dslots = (unsigned*)alloc(256*4);

  hipMemsetAsync(eslots, 0, 4*64*4, stream);
  hipMemsetAsync(dslots, 0, 256*4, stream);
  hipMemsetAsync(hbuf, 0, 2ull*64*512*2, stream);
  hipMemsetAsync(cbuf, 0, 64ull*512*4, stream);

  cast_k<<<4096, 256, 0, stream>>>(enc_Wih, wih_e, 2048*512);
  cast_k<<<4096, 256, 0, stream>>>(enc_Whh, whh_e, 2048*512);
  cast_k<<<4096, 256, 0, stream>>>(dec_Wih, wih_d, 2048*512);
  cast_k<<<4096, 256, 0, stream>>>(dec_Whh, whh_d, 2048*512);
  cast_k<<<2048, 256, 0, stream>>>(fc_W, fcw, 512*1024);
  split_attn_k<<<1024, 256, 0, stream>>>(attn_W, whq, weq);

  embed_k<<<512, 512, 0, stream>>>(x_enc, w_emb_e, encin, 64, 512, 0, 512, 0);
  embed_k<<<64, 512, 0, stream>>>(x_dec, w_emb_d, xs, 64, 144, 48, 48, 1);

  gemm_nt<<<dim3(16, 24), 256, 0, stream>>>(xs, wih_d, dec_b, xg, 3072, 2048, 512);

  for (int c = 0; c < 4; ++c){
    gemm_nt<<<dim3(16, 64), 256, 0, stream>>>(encin + (size_t)c*8192*512, wih_e, enc_b,
                                              encxw, 8192, 2048, 512);
    lstm_enc<<<128, 256, 0, stream>>>(encxw, whh_e, cbuf, hbuf, encout, c*128, 128, eslots);
  }

  gemm_nt<<<dim3(4, 256), 256, 0, stream>>>(encout, weq, attn_b, encin /*enc_part*/, 32768, 512, 512);

  lstm_dec<<<256, 256, 0, stream>>>(xg, whh_d, whq, fcw, fc_b, vvec,
                                    encin /*enc_part*/, encout, hbuf, cbuf,
                                    scp, ctxp, outsb, dslots);

  proj_k<<<84, 256, 0, stream>>>(outsb, proj_W, proj_b, out);
}

// Round 3
// 6205.064 us; speedup vs baseline: 1.5021x; 1.1010x over previous
//
#include <hip/hip_runtime.h>
#include <hip/hip_bf16.h>

// ---------------------------------------------------------------------------
// conv1d embed -> LSTM encoder (512 steps, B=64, H=512) -> attention decoder
// (48 steps) -> projection.
// Cross-block sync: FENCE-FREE slot barriers. All cross-block mutable data
// (h, scores, ctx, slots) uses relaxed agent-scope atomics (coherence-point
// ops, no L1/L2 staleness); producer drains with s_waitcnt vmcnt(0) before
// publishing its slot. No release/acquire fences -> no buffer_wbl2/buffer_inv
// -> L2 keeps read-only data (weights, encpart, encout) resident across steps.
// ---------------------------------------------------------------------------

typedef short bf16x8 __attribute__((ext_vector_type(8)));
typedef float f32x4 __attribute__((ext_vector_type(4)));

static __device__ __forceinline__ float bf2f(unsigned short u){
  return __uint_as_float(((unsigned)u) << 16);
}
static __device__ __forceinline__ unsigned short f2bf(float f){
  unsigned x = __float_as_uint(f);
  return (unsigned short)((x + 0x7fffu + ((x >> 16) & 1u)) >> 16);   // RNE
}
static __device__ __forceinline__ float sigm(float x){
  return __builtin_amdgcn_rcpf(1.f + __builtin_amdgcn_exp2f(-1.44269504f*x));
}
static __device__ __forceinline__ float tanh2(float x){
  return 1.f - 2.f*__builtin_amdgcn_rcpf(1.f + __builtin_amdgcn_exp2f(2.88539008f*x));
}

static __device__ __forceinline__ unsigned ldu(const unsigned* p){
  return __hip_atomic_load(p, __ATOMIC_RELAXED, __HIP_MEMORY_SCOPE_AGENT);
}
static __device__ __forceinline__ void stu(unsigned* p, unsigned v){
  __hip_atomic_store(p, v, __ATOMIC_RELAXED, __HIP_MEMORY_SCOPE_AGENT);
}
static __device__ __forceinline__ float ldf(const float* p){
  return __hip_atomic_load(p, __ATOMIC_RELAXED, __HIP_MEMORY_SCOPE_AGENT);
}
static __device__ __forceinline__ void adf(float* p, float v){
  (void)__hip_atomic_fetch_add(p, v, __ATOMIC_RELAXED, __HIP_MEMORY_SCOPE_AGENT);
}
static __device__ __forceinline__ bf16x8 ldh8(const unsigned* p){
  union { unsigned u[4]; bf16x8 v; } x;
  x.u[0] = ldu(p); x.u[1] = ldu(p+1); x.u[2] = ldu(p+2); x.u[3] = ldu(p+3);
  return x.v;
}
#define VMWAIT() __asm__ __volatile__("s_waitcnt vmcnt(0)" ::: "memory")

// Fence-free barrier: every wave drains its vmem (atomic stores reach the
// coherence point), then one relaxed slot store + relaxed poll.
static __device__ __forceinline__ void slot_barrier(unsigned* myslot, const unsigned* slots,
                                                    int nslots, unsigned target){
  VMWAIT();
  __syncthreads();
  if (threadIdx.x == 0) stu(myslot, target);
  if (threadIdx.x < 64){
    while (true){
      bool ok = true;
      for (int i = (int)threadIdx.x; i < nslots; i += 64)
        ok &= (ldu(&slots[i]) >= target);
      if (__all(ok)) break;
      __builtin_amdgcn_s_sleep(1);
    }
  }
  __syncthreads();
}

// ----------------------------- small utility kernels -----------------------

__global__ void cast_k(const float* __restrict__ src, unsigned short* __restrict__ dst, int n){
  int i = blockIdx.x*256 + threadIdx.x;
  if (i < n) dst[i] = f2bf(src[i]);
}

__global__ void split_attn_k(const float* __restrict__ aw,
                             unsigned short* __restrict__ wh, unsigned short* __restrict__ we){
  int i = blockIdx.x*256 + threadIdx.x;
  int nrow = i >> 9, k = i & 511;
  wh[i] = f2bf(aw[(size_t)nrow*1024 + k]);
  we[i] = f2bf(aw[(size_t)nrow*1024 + 512 + k]);
}

__global__ __launch_bounds__(512) void embed_k(const float* __restrict__ x,
    const float* __restrict__ wconv, unsigned short* __restrict__ out,
    int Bsz, int Lx, int l0, int lcount, int mode){
  __shared__ float wl[512*21];
  __shared__ float xl[66*7];
  int nch = (lcount + 63) / 64;
  int b = blockIdx.x / nch, ci = blockIdx.x % nch;
  int tid = threadIdx.x;
  for (int i = tid; i < 512*21; i += 512) wl[i] = wconv[i];
  int lstart = l0 + ci*64;
  int cnt = l0 + lcount - lstart; if (cnt > 64) cnt = 64;
  int nwin = (cnt + 2) * 7;
  for (int i = tid; i < nwin; i += 512){
    int wr = i / 7, c = i % 7;
    int gl = lstart - 1 + wr;
    gl = (gl + Lx) % Lx;
    xl[i] = x[((size_t)b*Lx + gl)*7 + c];
  }
  __syncthreads();
  int o = tid;
  float fe = (float)(o & ~1);
  float div = __expf(fe * -0.0179889461f);
  const float* wrow = &wl[o*21];
  for (int li = 0; li < cnt; ++li){
    int l = lstart + li;
    float acc = 0.f;
    #pragma unroll
    for (int c = 0; c < 7; ++c)
      #pragma unroll
      for (int kk = 0; kk < 3; ++kk)
        acc += xl[(li + kk)*7 + c] * wrow[c*3 + kk];
    float arg = (float)l * div;
    acc += (o & 1) ? cosf(arg) : sinf(arg);
    size_t oi = mode ? (((size_t)b*lcount + (l - l0))*512 + o)
                     : (((size_t)l*Bsz + b)*512 + o);
    out[oi] = f2bf(acc);
  }
}

// ----------------------------- bf16 NT GEMM --------------------------------
__global__ __launch_bounds__(256) void gemm_nt(const unsigned short* __restrict__ A,
    const unsigned short* __restrict__ Bw, const float* __restrict__ bias,
    unsigned short* __restrict__ C, int M, int N, int K){
  __shared__ __align__(16) unsigned short Asm[128*40];
  __shared__ __align__(16) unsigned short Bsm[128*40];
  const int tid = threadIdx.x;
  const int m0 = blockIdx.y * 128, n0 = blockIdx.x * 128;
  const int lane = tid & 63;
  const int wid = tid >> 6;
  const int wm = (wid >> 1) * 64, wn = (wid & 1) * 64;
  const int fr = lane & 15, q = lane >> 4;
  f32x4 acc[4][4];
  #pragma unroll
  for (int i=0;i<4;i++)
    #pragma unroll
    for(int j=0;j<4;j++) acc[i][j] = (f32x4){0.f,0.f,0.f,0.f};
  for (int k0 = 0; k0 < K; k0 += 32){
    #pragma unroll
    for (int c = 0; c < 2; ++c){
      int ch = tid + c*256;
      int r = ch >> 2, s = (ch & 3) * 8;
      *(uint4*)&Asm[r*40 + s] = *(const uint4*)&A[(size_t)(m0 + r)*K + k0 + s];
      *(uint4*)&Bsm[r*40 + s] = *(const uint4*)&Bw[(size_t)(n0 + r)*K + k0 + s];
    }
    __syncthreads();
    bf16x8 af[4], bfv[4];
    #pragma unroll
    for (int i=0;i<4;i++){
      af[i]  = *(const bf16x8*)&Asm[(wm + i*16 + fr)*40 + q*8];
      bfv[i] = *(const bf16x8*)&Bsm[(wn + i*16 + fr)*40 + q*8];
    }
    #pragma unroll
    for (int i=0;i<4;i++)
      #pragma unroll
      for (int j=0;j<4;j++)
        acc[i][j] = __builtin_amdgcn_mfma_f32_16x16x32_bf16(af[i], bfv[j], acc[i][j], 0,0,0);
    __syncthreads();
  }
  #pragma unroll
  for (int i=0;i<4;i++){
    #pragma unroll
    for (int j=0;j<4;j++){
      int n = n0 + wn + j*16 + fr;
      float bv = bias ? bias[n] : 0.f;
      #pragma unroll
      for (int r=0;r<4;r++){
        int m = m0 + wm + i*16 + q*4 + r;
        C[(size_t)m*N + n] = f2bf(acc[i][j][r] + bv);
      }
    }
  }
}

// ----------------------------- encoder LSTM --------------------------------
// 128 blocks = 4 batch-groups (16 batches) x 32 unit-blocks (16 units each).
// h exchanged via relaxed agent atomics (dword-packed bf16 pairs).
__global__ __launch_bounds__(256) void lstm_enc(
    const unsigned short* __restrict__ xw,    // [nsteps][64][2048] bf16 (bias folded)
    const unsigned short* __restrict__ whh,   // [2048][512] bf16
    float* __restrict__ cbuf,                 // [64][512]
    unsigned* __restrict__ hbuf,              // [2][64][256] dwords (bf16 pairs)
    unsigned short* __restrict__ encout,      // [64][512][512] bf16
    int t0, int nsteps, unsigned* __restrict__ slots){
  __shared__ __align__(16) unsigned short wlds[64*516];
  __shared__ __align__(16) unsigned short hblds[16*516];
  __shared__ float gbuf[16*68];
  const int tid = threadIdx.x;
  const int g = blockIdx.x >> 5;      // batch group 0..3
  const int j = blockIdx.x & 31;      // unit block 0..31
  const int b0 = g*16, u0 = j*16;
  for (int idx = tid; idx < 64*64; idx += 256){
    int n = idx >> 6, ch = idx & 63;
    int R = (n >> 4)*512 + u0 + (n & 15);
    *(uint4*)&wlds[n*516 + ch*8] = *(const uint4*)&whh[(size_t)R*512 + ch*8];
  }
  __syncthreads();
  const int lane = tid & 63, wv = tid >> 6, fr = lane & 15, q = lane >> 4;
  const int m = tid >> 4, j2 = tid & 15;
  float cst = cbuf[(b0 + m)*512 + u0 + j2];
  unsigned* myslot = slots + g*64 + j;
  const unsigned* gslots = slots + g*64;
  // prefetch xw for step 0
  unsigned short px0, px1, px2, px3;
  {
    size_t xi = ((size_t)(b0 + m))*2048 + u0 + j2;
    px0 = xw[xi]; px1 = xw[xi + 512]; px2 = xw[xi + 1024]; px3 = xw[xi + 1536];
  }
  for (int s = 0; s < nsteps; ++s){
    const int t = t0 + s;
    const int rp = t & 1, wp = rp ^ 1;
    // stage h(group) into LDS via atomic dword loads
    {
      const unsigned* hbu = hbuf + (size_t)rp*(64*256) + (size_t)b0*256;
      #pragma unroll
      for (int it = 0; it < 16; ++it){
        int idx = it*256 + tid;
        unsigned v = ldu(&hbu[idx]);
        int m2 = idx >> 8, u2 = idx & 255;
        *(unsigned*)&hblds[m2*516 + u2*2] = v;
      }
    }
    __syncthreads();
    f32x4 acc = {0.f,0.f,0.f,0.f};
    #pragma unroll
    for (int k0 = 0; k0 < 512; k0 += 32){
      bf16x8 av = *(const bf16x8*)&hblds[fr*516 + k0 + q*8];
      bf16x8 bv = *(const bf16x8*)&wlds[(wv*16 + fr)*516 + k0 + q*8];
      acc = __builtin_amdgcn_mfma_f32_16x16x32_bf16(av, bv, acc, 0,0,0);
    }
    #pragma unroll
    for (int r = 0; r < 4; ++r)
      gbuf[(q*4 + r)*68 + wv*16 + fr] = acc[r];
    __syncthreads();
    {
      float gi = gbuf[m*68 + j2]      + bf2f(px0);
      float gf = gbuf[m*68 + 16 + j2] + bf2f(px1);
      float gg = gbuf[m*68 + 32 + j2] + bf2f(px2);
      float go = gbuf[m*68 + 48 + j2] + bf2f(px3);
      float cc = sigm(gf)*cst + sigm(gi)*tanh2(gg);
      float hh = sigm(go)*tanh2(cc);
      cst = cc;
      unsigned short hv = f2bf(hh);
      // pack bf16 pair with neighbor lane, even-unit lane stores dword atomic
      unsigned other = (unsigned)__shfl_xor((int)(unsigned)hv, 1);
      if ((j2 & 1) == 0)
        stu(&hbuf[(size_t)wp*(64*256) + (size_t)(b0+m)*256 + ((u0 + j2) >> 1)],
            ((unsigned)hv) | (other << 16));
      encout[((size_t)(b0+m)*512 + t)*512 + u0 + j2] = hv;
    }
    if (s == nsteps - 1) cbuf[(b0+m)*512 + u0 + j2] = cst;
    else {
      size_t xi = ((size_t)(s+1)*64 + b0 + m)*2048 + u0 + j2;
      px0 = xw[xi]; px1 = xw[xi + 512]; px2 = xw[xi + 1024]; px3 = xw[xi + 1536];
    }
    // ensure gbuf not overwritten before all threads consumed it next step:
    // (slot_barrier's syncthreads handles it)
    slot_barrier(myslot, gslots, 32, (unsigned)(t + 1));
  }
}

// ----------------------------- decoder -------------------------------------
// 256 blocks x 256 thr, 48 steps, 3 fence-free barriers/step.
// Phase A: blocks 0-127 gates (4 units each); blocks 128-255 fc of step t-1.
// Phase C: all blocks (ab=blk>>2, ks=blk&3): hwh k-slice via MFMA + partial
//          scores atomicAdd'ed into per-step score buffer.
// Phase D: softmax + ctx partial atomicAdd into per-step ctx buffer.
__global__ __launch_bounds__(256) void lstm_dec(
    const unsigned short* __restrict__ xg,      // [64][48][2048] bf16 (bias folded)
    const unsigned short* __restrict__ whh,     // dec_Whh bf16 [2048][512]
    const unsigned short* __restrict__ whq,     // Wh bf16 [512][512]
    const unsigned short* __restrict__ fcw,     // fc_W bf16 [512][1024]
    const float* __restrict__ fcb, const float* __restrict__ vvec,
    const unsigned short* __restrict__ encpart, // [64*512][512] bf16
    const unsigned short* __restrict__ encout,  // [64*512][512] bf16
    unsigned* __restrict__ hbuf,                // [2][64][256] dwords
    float* __restrict__ cbuf,
    float* __restrict__ scb,                    // [48][64][512] zeroed
    float* __restrict__ ctx48,                  // [48][64][512] zeroed
    unsigned short* __restrict__ outs, unsigned* __restrict__ slots){
  __shared__ __align__(16) unsigned short Whsl[128*516];
  __shared__ __align__(16) unsigned short wshare[16*516];
  __shared__ __align__(16) unsigned short hlds[512];
  __shared__ __align__(16) float hwhlds[128];
  __shared__ float gbuf[64*17];
  __shared__ float sclds[512];
  __shared__ float awlds[128];
  __shared__ __align__(16) float vlds[512];
  __shared__ float red[8];
  const int tid = threadIdx.x, blk = blockIdx.x;
  const int lane = tid & 63, wv = tid >> 6, fr = lane & 15, q = lane >> 4;
  const int ab = blk >> 2, ks = blk & 3;
  for (int idx = tid; idx < 128*64; idx += 256){
    int r = idx >> 6, ch = idx & 63;
    *(uint4*)&Whsl[r*516 + ch*8] = *(const uint4*)&whq[((size_t)(ks*128 + r))*512 + ch*8];
  }
  if (blk < 128){
    for (int idx = tid; idx < 16*64; idx += 256){
      int n = idx >> 6, ch = idx & 63;
      int R = (n >> 2)*512 + blk*4 + (n & 3);   // [i(4), f(4), g(4), o(4)]
      *(uint4*)&wshare[n*516 + ch*8] = *(const uint4*)&whh[(size_t)R*512 + ch*8];
    }
  } else {
    int fb = blk - 128;
    for (int idx = tid; idx < 4*128; idx += 256){
      int r = idx >> 7, ch = idx & 127;
      *(uint4*)&wshare[r*1032 + ch*8] = *(const uint4*)&fcw[((size_t)(fb*4 + r))*1024 + ch*8];
    }
  }
  vlds[tid] = vvec[tid]; vlds[tid+256] = vvec[tid+256];
  __syncthreads();
  float vsum = 0.f;
  for (int k = 0; k < 128; ++k) vsum += vlds[ks*128 + k];
  __syncthreads();
  vlds[tid] *= -2.f; vlds[tid+256] *= -2.f;
  const int um = tid >> 2, uj = tid & 3;
  float cst = (blk < 128) ? cbuf[um*512 + blk*4 + uj] : 0.f;
  unsigned* myslot = slots + blk;

  auto do_fc = [&](int tt){
    int fb = blk - 128, r0 = fb*4;
    int fm = tid >> 2, qq = tid & 3;
    int hp = (tt + 1) & 1;
    const unsigned* hb = hbuf + (size_t)hp*(64*256) + (size_t)fm*256;
    const float* cpb = &ctx48[((size_t)tt*64 + fm)*512];
    float s4[4] = {0.f,0.f,0.f,0.f};
    for (int c = 0; c < 16; ++c){
      int kk = (c*4 + qq)*8;
      bf16x8 h8 = ldh8(&hb[kk >> 1]);
      float hf[8];
      #pragma unroll
      for (int e=0;e<8;e++) hf[e] = bf2f(((const unsigned short*)&h8)[e]);
      #pragma unroll
      for (int r = 0; r < 4; ++r){
        bf16x8 w8 = *(const bf16x8*)&wshare[r*1032 + kk];
        #pragma unroll
        for (int e = 0; e < 8; ++e)
          s4[r] += hf[e] * bf2f(((const unsigned short*)&w8)[e]);
      }
    }
    for (int c = 0; c < 16; ++c){
      int kk = (c*4 + qq)*8;
      float cf[8];
      #pragma unroll
      for (int e = 0; e < 8; ++e) cf[e] = ldf(&cpb[kk + e]);
      #pragma unroll
      for (int r = 0; r < 4; ++r){
        bf16x8 w8 = *(const bf16x8*)&wshare[r*1032 + 512 + kk];
        #pragma unroll
        for (int e = 0; e < 8; ++e)
          s4[r] += cf[e] * bf2f(((const unsigned short*)&w8)[e]);
      }
    }
    #pragma unroll
    for (int r = 0; r < 4; ++r){
      s4[r] += __shfl_xor(s4[r], 1);
      s4[r] += __shfl_xor(s4[r], 2);
    }
    if (qq == 0){
      #pragma unroll
      for (int r = 0; r < 4; ++r)
        outs[((size_t)fm*48 + tt)*512 + r0 + r] = f2bf(s4[r] + fcb[r0 + r]);
    }
  };

  for (int t = 0; t < 48; ++t){
    const int rp = t & 1, wp = rp ^ 1;
    // ---- phase A: gates (0-127) | fc of t-1 (128-255)
    if (blk < 128){
      const unsigned* hb = hbuf + (size_t)rp*(64*256);
      f32x4 a0 = {0.f,0.f,0.f,0.f};
      #pragma unroll
      for (int k0 = 0; k0 < 512; k0 += 32){
        bf16x8 av = ldh8(&hb[(size_t)(wv*16 + fr)*256 + (k0 >> 1) + q*4]);
        bf16x8 bv = *(const bf16x8*)&wshare[fr*516 + k0 + q*8];
        a0 = __builtin_amdgcn_mfma_f32_16x16x32_bf16(av, bv, a0, 0,0,0);
      }
      #pragma unroll
      for (int r = 0; r < 4; ++r) gbuf[(wv*16 + q*4 + r)*17 + fr] = a0[r];
      __syncthreads();
      {
        const float* gb = &gbuf[um*17];
        size_t xi = ((size_t)um*48 + t)*2048 + blk*4 + uj;
        float gi = gb[uj]      + bf2f(xg[xi]);
        float gf = gb[4 + uj]  + bf2f(xg[xi + 512]);
        float gg = gb[8 + uj]  + bf2f(xg[xi + 1024]);
        float go = gb[12 + uj] + bf2f(xg[xi + 1536]);
        float cc = sigm(gf)*cst + sigm(gi)*tanh2(gg);
        float hh = sigm(go)*tanh2(cc);
        cst = cc;
        unsigned short hv = f2bf(hh);
        unsigned other = (unsigned)__shfl_xor((int)(unsigned)hv, 1);
        if ((uj & 1) == 0)
          stu(&hbuf[(size_t)wp*(64*256) + (size_t)um*256 + ((blk*4 + uj) >> 1)],
              ((unsigned)hv) | (other << 16));
      }
    } else if (t > 0){
      do_fc(t - 1);
    }
    slot_barrier(myslot, slots, 256, 3u*t + 1);
    // ---- phase C: hwh k-slice (MFMA) + partial scores (atomicAdd)
    {
      unsigned hv = ldu(&hbuf[(size_t)wp*(64*256) + (size_t)ab*256 + tid]);
      *(unsigned*)&hlds[tid*2] = hv;
      __syncthreads();
      f32x4 h0 = {0.f,0.f,0.f,0.f}, h1 = {0.f,0.f,0.f,0.f};
      #pragma unroll
      for (int k0 = 0; k0 < 512; k0 += 32){
        bf16x8 av = *(const bf16x8*)&hlds[k0 + q*8];   // broadcast across A-rows
        bf16x8 b0 = *(const bf16x8*)&Whsl[(wv*32 + fr)*516 + k0 + q*8];
        bf16x8 b1 = *(const bf16x8*)&Whsl[(wv*32 + 16 + fr)*516 + k0 + q*8];
        h0 = __builtin_amdgcn_mfma_f32_16x16x32_bf16(av, b0, h0, 0,0,0);
        h1 = __builtin_amdgcn_mfma_f32_16x16x32_bf16(av, b1, h1, 0,0,0);
      }
      if (q == 0){
        hwhlds[wv*32 + fr]      = 2.88539008f * h0[0];   // pre-scaled for exp2
        hwhlds[wv*32 + 16 + fr] = 2.88539008f * h1[0];
      }
      __syncthreads();
      const unsigned short* ep0 = encpart + ((size_t)ab*512 + tid)*512 + ks*128;
      const unsigned short* ep1 = ep0 + (size_t)256*512;
      float sacc0 = vsum, sacc1 = vsum;
      for (int kk = 0; kk < 128; kk += 8){
        bf16x8 e0 = *(const bf16x8*)&ep0[kk];
        bf16x8 e1 = *(const bf16x8*)&ep1[kk];
        float4 hwa = *(const float4*)&hwhlds[kk];
        float4 hwb = *(const float4*)&hwhlds[kk+4];
        float4 va  = *(const float4*)&vlds[ks*128 + kk];
        float4 vb  = *(const float4*)&vlds[ks*128 + kk + 4];
        float hw[8] = {hwa.x,hwa.y,hwa.z,hwa.w,hwb.x,hwb.y,hwb.z,hwb.w};
        float vv[8] = {va.x,va.y,va.z,va.w,vb.x,vb.y,vb.z,vb.w};
        #pragma unroll
        for (int e = 0; e < 8; ++e){
          float a0 = fmaf(bf2f(((const unsigned short*)&e0)[e]), 2.88539008f, hw[e]);
          float a1 = fmaf(bf2f(((const unsigned short*)&e1)[e]), 2.88539008f, hw[e]);
          sacc0 += vv[e]*__builtin_amdgcn_rcpf(1.f + __builtin_amdgcn_exp2f(a0));
          sacc1 += vv[e]*__builtin_amdgcn_rcpf(1.f + __builtin_amdgcn_exp2f(a1));
        }
      }
      float* sb = &scb[((size_t)t*64 + ab)*512];
      adf(&sb[tid], sacc0);
      adf(&sb[tid + 256], sacc1);
    }
    slot_barrier(myslot, slots, 256, 3u*t + 2);
    // ---- phase D: softmax + ctx partial (lc = ks)
    {
      const int lc = ks;
      const float* sb = &scb[((size_t)t*64 + ab)*512];
      float v0 = ldf(&sb[tid]), v1 = ldf(&sb[tid + 256]);
      sclds[tid] = v0; sclds[tid+256] = v1;
      float mx = fmaxf(v0, v1);
      #pragma unroll
      for (int off=32; off; off>>=1) mx = fmaxf(mx, __shfl_xor(mx, off));
      if (lane == 0) red[wv] = mx;
      __syncthreads();
      mx = fmaxf(fmaxf(red[0],red[1]), fmaxf(red[2],red[3]));
      __syncthreads();
      float ps = __expf(v0 - mx) + __expf(v1 - mx);
      #pragma unroll
      for (int off=32; off; off>>=1) ps += __shfl_xor(ps, off);
      if (lane == 0) red[wv] = ps;
      __syncthreads();
      float inv = 1.f / (red[0]+red[1]+red[2]+red[3]);
      if (tid < 128) awlds[tid] = __expf(sclds[lc*128 + tid] - mx) * inv;
      __syncthreads();
      float ax = 0.f, ay = 0.f;
      const unsigned short* eo = encout + ((size_t)ab*512 + lc*128)*512 + 2*tid;
      #pragma unroll 4
      for (int il = 0; il < 128; ++il){
        float aww = awlds[il];
        unsigned ee = *(const unsigned*)(eo + (size_t)il*512);
        ax += aww * __uint_as_float((ee & 0xffffu) << 16);
        ay += aww * __uint_as_float(ee & 0xffff0000u);
      }
      float* cb = &ctx48[((size_t)t*64 + ab)*512];
      adf(&cb[2*tid], ax);
      adf(&cb[2*tid + 1], ay);
    }
    slot_barrier(myslot, slots, 256, 3u*t + 3);
  }
  if (blk >= 128) do_fc(47);
}

// ----------------------------- projection ----------------------------------
__global__ void proj_k(const unsigned short* __restrict__ outs,
                       const float* __restrict__ pw, const float* __restrict__ pb,
                       float* __restrict__ out){
  int gid = blockIdx.x*256 + threadIdx.x;
  if (gid >= 64*48*7) return;
  int row = gid / 7, oc = gid % 7;
  const unsigned short* orow = outs + (size_t)row*512;
  const float* wrow = pw + oc*512;
  float s = pb[oc];
  for (int k = 0; k < 512; k += 8){
    bf16x8 o8 = *(const bf16x8*)&orow[k];
    #pragma unroll
    for (int e=0;e<8;e++) s += bf2f(((unsigned short*)&o8)[e]) * wrow[k+e];
  }
  out[gid] = s;
}

// ----------------------------- launch --------------------------------------
extern "C" void kernel_launch(void* const* d_in, const int* in_sizes, int n_in,
                              void* d_out, int out_size, void* d_ws, size_t ws_size,
                              hipStream_t stream){
  (void)in_sizes; (void)n_in; (void)out_size; (void)ws_size;
  const float* x_enc   = (const float*)d_in[0];
  const float* x_dec   = (const float*)d_in[1];
  const float* w_emb_e = (const float*)d_in[2];
  const float* w_emb_d = (const float*)d_in[3];
  const float* enc_Wih = (const float*)d_in[4];
  const float* enc_Whh = (const float*)d_in[5];
  const float* enc_b   = (const float*)d_in[6];
  const float* dec_Wih = (const float*)d_in[7];
  const float* dec_Whh = (const float*)d_in[8];
  const float* dec_b   = (const float*)d_in[9];
  const float* attn_W  = (const float*)d_in[10];
  const float* attn_b  = (const float*)d_in[11];
  const float* vvec    = (const float*)d_in[12];
  const float* fc_W    = (const float*)d_in[13];
  const float* fc_b    = (const float*)d_in[14];
  const float* proj_W  = (const float*)d_in[15];
  const float* proj_b  = (const float*)d_in[16];
  float* out = (float*)d_out;

  char* ws = (char*)d_ws;
  size_t off = 0;
  auto alloc = [&](size_t bytes)->char*{
    char* p = ws + off;
    off = (off + bytes + 255) & ~(size_t)255;
    return p;
  };
  unsigned short* encxw  = (unsigned short*)alloc(128ull*64*2048*2);
  unsigned short* encin  = (unsigned short*)alloc(512ull*64*512*2);  // embed; reused as enc_part
  unsigned short* encout = (unsigned short*)alloc(64ull*512*512*2);
  unsigned short* xs     = (unsigned short*)alloc(64ull*48*512*2);
  unsigned short* xg     = (unsigned short*)alloc(64ull*48*2048*2);
  unsigned short* outsb  = (unsigned short*)alloc(64ull*48*512*2);
  unsigned short* wih_e  = (unsigned short*)alloc(2048ull*512*2);
  unsigned short* whh_e  = (unsigned short*)alloc(2048ull*512*2);
  unsigned short* wih_d  = (unsigned short*)alloc(2048ull*512*2);
  unsigned short* whh_d  = (unsigned short*)alloc(2048ull*512*2);
  unsigned short* whq    = (unsigned short*)alloc(512ull*512*2);
  unsigned short* weq    = (unsigned short*)alloc(512ull*512*2);
  unsigned short* fcw    = (unsigned short*)alloc(512ull*1024*2);
  unsigned* hbuf  = (unsigned*)alloc(2ull*64*256*4);
  float* cbuf   = (float*)alloc(64ull*512*4);
  float* scb    = (float*)alloc(48ull*64*512*4);
  float* ctx48  = (float*)alloc(48ull*64*512*4);
  unsigned* eslots = (unsigned*)alloc(4*64*4);
  unsigned* dslots = (unsigned*)alloc(256*4);

  hipMemsetAsync(eslots, 0, 4*64*4, stream);
  hipMemsetAsync(dslots, 0, 256*4, stream);
  hipMemsetAsync(hbuf, 0, 2ull*64*256*4, stream);
  hipMemsetAsync(cbuf, 0, 64ull*512*4, stream);
  hipMemsetAsync(scb, 0, 48ull*64*512*4, stream);
  hipMemsetAsync(ctx48, 0, 48ull*64*512*4, stream);

  cast_k<<<4096, 256, 0, stream>>>(enc_Wih, wih_e, 2048*512);
  cast_k<<<4096, 256, 0, stream>>>(enc_Whh, whh_e, 2048*512);
  cast_k<<<4096, 256, 0, stream>>>(dec_Wih, wih_d, 2048*512);
  cast_k<<<4096, 256, 0, stream>>>(dec_Whh, whh_d, 2048*512);
  cast_k<<<2048, 256, 0, stream>>>(fc_W, fcw, 512*1024);
  split_attn_k<<<1024, 256, 0, stream>>>(attn_W, whq, weq);

  embed_k<<<512, 512, 0, stream>>>(x_enc, w_emb_e, encin, 64, 512, 0, 512, 0);
  embed_k<<<64, 512, 0, stream>>>(x_dec, w_emb_d, xs, 64, 144, 48, 48, 1);

  gemm_nt<<<dim3(16, 24), 256, 0, stream>>>(xs, wih_d, dec_b, xg, 3072, 2048, 512);

  for (int c = 0; c < 4; ++c){
    gemm_nt<<<dim3(16, 64), 256, 0, stream>>>(encin + (size_t)c*8192*512, wih_e, enc_b,
                                              encxw, 8192, 2048, 512);
    lstm_enc<<<128, 256, 0, stream>>>(encxw, whh_e, cbuf, hbuf, encout, c*128, 128, eslots);
  }

  gemm_nt<<<dim3(4, 256), 256, 0, stream>>>(encout, weq, attn_b, encin /*enc_part*/, 32768, 512, 512);

  lstm_dec<<<256, 256, 0, stream>>>(xg, whh_d, whq, fcw, fc_b, vvec,
                                    encin /*enc_part*/, encout, hbuf, cbuf,
                                    scb, ctx48, outsb, dslots);

  proj_k<<<84, 256, 0, stream>>>(outsb, proj_W, proj_b, out);
}